// Round 1
// baseline (306.755 us; speedup 1.0000x reference)
//
#include <hip/hip_runtime.h>

#define BS 64
#define SEQ 2048
#define LQ 128
#define NH 128

typedef short bf16x8 __attribute__((ext_vector_type(8)));
typedef float f32x4 __attribute__((ext_vector_type(4)));

__device__ __forceinline__ unsigned short f2bf(float f) {
  unsigned u = __float_as_uint(f);
  u = (u + 0x7FFFu + ((u >> 16) & 1u)) >> 16;
  return (unsigned short)u;
}
__device__ __forceinline__ float sigm(float x) { return 1.f / (1.f + __expf(-x)); }
__device__ __forceinline__ float tanh_f(float x) { return 1.f - 2.f / (1.f + __expf(2.f * x)); }
__device__ __forceinline__ float gelu_f(float x) { return 0.5f * x * (1.f + erff(x * 0.70710678118654752f)); }
__device__ __forceinline__ float rdlane(float v, int l) {
  return __int_as_float(__builtin_amdgcn_readlane(__float_as_int(v), l));
}

// ---------------- mask dtype detection / normalization ----------------
__global__ void k_detect(const unsigned* __restrict__ raw, int* __restrict__ flag) {
  int tid = threadIdx.x;  // 64 threads, 1 wave
  int isf = 0, isb = 0;
  for (int k = 0; k < 4; ++k) {
    unsigned w = raw[tid + k * 64];
    isf |= (w == 0x3F800000u);
    isb |= (w > 1u);
  }
  isf = __any(isf);
  isb = __any(isb);
  if (tid == 0) *flag = isf ? 2 : (isb ? 1 : 0);
}

__global__ __launch_bounds__(256) void k_norm(const void* __restrict__ raw,
                                              const int* __restrict__ flag,
                                              float* __restrict__ mf) {
  int i = blockIdx.x * 256 + threadIdx.x;
  if (i >= BS * SEQ) return;
  int fl = *flag;
  float v;
  if (fl == 2)      v = (((const float*)raw)[i] != 0.f) ? 1.f : 0.f;
  else if (fl == 1) v = (((const unsigned char*)raw)[i] != 0) ? 1.f : 0.f;
  else              v = (((const int*)raw)[i] != 0) ? 1.f : 0.f;
  mf[i] = v;
}

// ---------------- Q projection (q_emb @ q_w^T + q_b) -> bf16 [4][128][32] ----------------
__global__ __launch_bounds__(256) void k_qproj(
    const float* __restrict__ qw, const float* __restrict__ qb,
    const float* __restrict__ lw, const float* __restrict__ lb,
    const float* __restrict__ pw, const float* __restrict__ pb,
    unsigned short* __restrict__ qbf) {
  __shared__ float emb[16 * 132];
  __shared__ float Ac[128], Bc[128];
  const int tid = threadIdx.x, blk = blockIdx.x;  // 8 blocks x 16 lq
  if (tid < 128) {
    Ac[tid] = (tid == 0) ? lw[0] : pw[tid - 1];
    Bc[tid] = (tid == 0) ? lb[0] : pb[tid - 1];
  }
  __syncthreads();
  {
    int lq = tid >> 4, e0 = (tid & 15) * 8;
    float tv = (float)(blk * 16 + lq) * (1.f / 127.f);
#pragma unroll
    for (int k = 0; k < 8; ++k) {
      int e = e0 + k;
      float arg = fmaf(tv, Ac[e], Bc[e]);
      emb[lq * 132 + e] = (e == 0) ? arg : __sinf(arg);
    }
  }
  __syncthreads();
  const int c = tid & 127, lh = tid >> 7;
  float acc[8];
#pragma unroll
  for (int i = 0; i < 8; ++i) acc[i] = qb[c];
  for (int e4 = 0; e4 < 32; ++e4) {
    float4 wv = *(const float4*)(qw + c * 128 + e4 * 4);
#pragma unroll
    for (int i = 0; i < 8; ++i) {
      const float* er = &emb[(lh * 8 + i) * 132 + e4 * 4];
      acc[i] += wv.x * er[0] + wv.y * er[1] + wv.z * er[2] + wv.w * er[3];
    }
  }
#pragma unroll
  for (int i = 0; i < 8; ++i) {
    int lq = blk * 16 + lh * 8 + i;
    qbf[((c >> 5) * LQ + lq) * 32 + (c & 31)] = f2bf(acc[i]);
  }
}

// ---------------- fold att_out(8->128) ∘ wih(128->384) into FW[384][8] + const ----------------
__global__ __launch_bounds__(384) void k_fold(
    const float* __restrict__ wih, const float* __restrict__ bih,
    const float* __restrict__ aow, const float* __restrict__ aob,
    float* __restrict__ fwc) {
  const int g = threadIdx.x;
  float fw[8];
#pragma unroll
  for (int c = 0; c < 8; ++c) fw[c] = 0.f;
  float cg = bih[g];
  for (int j = 0; j < 128; ++j) {
    float w = wih[g * 128 + j];
    cg = fmaf(w, aob[j], cg);
#pragma unroll
    for (int c = 0; c < 8; ++c) fw[c] = fmaf(w, aow[j * 8 + c], fw[c]);
  }
#pragma unroll
  for (int c = 0; c < 8; ++c) fwc[g * 12 + c] = fw[c];
  fwc[g * 12 + 8] = cg;
}

// ---------------- fused attention per (b,h): embed -> proj(MFMA) -> scores(MFMA) -> online softmax ----------------
__global__ __launch_bounds__(256) void k_attn(
    const float* __restrict__ Xfa, const float* __restrict__ maskf,
    const float* __restrict__ fav,
    const float* __restrict__ kw, const float* __restrict__ kb,
    const float* __restrict__ lw, const float* __restrict__ lb,
    const float* __restrict__ pw, const float* __restrict__ pb,
    const unsigned short* __restrict__ qbf,
    float* __restrict__ attn_out) {
  __shared__ unsigned short kemb[64 * 136];  // bf16, stride 136 -> even 16B-slot spread
  __shared__ unsigned short kwl[32 * 136];   // bf16 k_w head slice
  __shared__ unsigned short ktl[64 * 40];    // bf16 projected K tile, stride 40
  __shared__ float xt[64], mtl[64], kbl[32], Ac[128], Bc[128];

  const int tid = threadIdx.x;
  const int lane = tid & 63, wave = tid >> 6;
  const int l15 = lane & 15, kg = lane >> 4;
  const int b = blockIdx.x >> 2, h = blockIdx.x & 3;
  const float KSCALE = 2.3873241463784303f;   // 1/radians(24)
  const float SCALE = 0.17677669529663687f;   // 1/sqrt(32)

  if (tid < 128) {
    Ac[tid] = (tid == 0) ? lw[0] : pw[tid - 1];
    Bc[tid] = (tid == 0) ? lb[0] : pb[tid - 1];
  }
  if (tid < 32) kbl[tid] = kb[h * 32 + tid];
  for (int rep = 0; rep < 2; ++rep) {
    int idx = rep * 256 + tid;  // 512 chunks of 8
    int d = idx >> 4, e0 = (idx & 15) * 8;
    const float* src = kw + (h * 32 + d) * 128 + e0;
    float4 s0 = *(const float4*)(src);
    float4 s1 = *(const float4*)(src + 4);
    bf16x8 v;
    v[0] = (short)f2bf(s0.x); v[1] = (short)f2bf(s0.y);
    v[2] = (short)f2bf(s0.z); v[3] = (short)f2bf(s0.w);
    v[4] = (short)f2bf(s1.x); v[5] = (short)f2bf(s1.y);
    v[6] = (short)f2bf(s1.z); v[7] = (short)f2bf(s1.w);
    *(bf16x8*)&kwl[d * 136 + e0] = v;
  }
  // Q A-fragments (persistent): A row = lane%16, k-run = (lane/16)*8
  bf16x8 qa[2];
#pragma unroll
  for (int mt = 0; mt < 2; ++mt) {
    int qrow = (wave * 2 + mt) * 16 + l15;
    qa[mt] = *(const bf16x8*)(qbf + (h * 128 + qrow) * 32 + kg * 8);
  }
  float sm[2][4], slv[2][4], sav[2][4];
#pragma unroll
  for (int mt = 0; mt < 2; ++mt)
#pragma unroll
    for (int r = 0; r < 4; ++r) { sm[mt][r] = -1e30f; slv[mt][r] = 0.f; sav[mt][r] = 0.f; }
  __syncthreads();

  for (int t32 = 0; t32 < 32; ++t32) {
    const int s0 = t32 * 64;
    // A1: time-embed 64 rows -> kemb (bf16), stage X/mask
    {
      int r = tid & 63, cb2 = tid >> 6;
      float tv = fav[b * SEQ + s0 + r] * KSCALE;
#pragma unroll
      for (int u = 0; u < 4; ++u) {
        bf16x8 v;
#pragma unroll
        for (int k = 0; k < 8; ++k) {
          int e = cb2 * 32 + u * 8 + k;
          float arg = fmaf(tv, Ac[e], Bc[e]);
          float val = (e == 0) ? arg : __sinf(arg);
          v[k] = (short)f2bf(val);
        }
        *(bf16x8*)&kemb[r * 136 + cb2 * 32 + u * 8] = v;
      }
      if (tid < 64) {
        xt[tid] = Xfa[b * SEQ + s0 + tid];
        mtl[tid] = maskf[b * SEQ + s0 + tid];
      }
    }
    __syncthreads();
    // A2: K projection, wave w owns s-rows [w*16, w*16+16)
#pragma unroll
    for (int nt = 0; nt < 2; ++nt) {
      f32x4 acc = {0.f, 0.f, 0.f, 0.f};
#pragma unroll
      for (int kp = 0; kp < 4; ++kp) {
        bf16x8 a = *(const bf16x8*)&kemb[(wave * 16 + l15) * 136 + kp * 32 + kg * 8];
        bf16x8 bb = *(const bf16x8*)&kwl[(nt * 16 + l15) * 136 + kp * 32 + kg * 8];
        acc = __builtin_amdgcn_mfma_f32_16x16x32_bf16(a, bb, acc, 0, 0, 0);
      }
      int d = nt * 16 + l15;
      float kbv = kbl[d];
#pragma unroll
      for (int r = 0; r < 4; ++r) {
        int srow = wave * 16 + kg * 4 + r;  // D row = (lane/16)*4 + reg
        ktl[srow * 40 + d] = f2bf(acc[r] + kbv);
      }
    }
    __syncthreads();
    // B: scores (Q 32 rows/wave x 64 s) + per-lane online softmax
    {
      float xv[4], mv[4];
      f32x4 D[2][4];
#pragma unroll
      for (int nt2 = 0; nt2 < 4; ++nt2) {
        int scol = nt2 * 16 + l15;
        xv[nt2] = xt[scol];
        mv[nt2] = mtl[scol];
        bf16x8 bk = *(const bf16x8*)&ktl[scol * 40 + kg * 8];
#pragma unroll
        for (int mt = 0; mt < 2; ++mt) {
          f32x4 z = {0.f, 0.f, 0.f, 0.f};
          D[mt][nt2] = __builtin_amdgcn_mfma_f32_16x16x32_bf16(qa[mt], bk, z, 0, 0, 0);
        }
      }
#pragma unroll
      for (int mt = 0; mt < 2; ++mt)
#pragma unroll
        for (int r = 0; r < 4; ++r) {
          float vm0 = (mv[0] != 0.f) ? D[mt][0][r] * SCALE : -1e30f;
          float vm1 = (mv[1] != 0.f) ? D[mt][1][r] * SCALE : -1e30f;
          float vm2 = (mv[2] != 0.f) ? D[mt][2][r] * SCALE : -1e30f;
          float vm3 = (mv[3] != 0.f) ? D[mt][3][r] * SCALE : -1e30f;
          float tmax = fmaxf(fmaxf(vm0, vm1), fmaxf(vm2, vm3));
          float mold = sm[mt][r];
          float mnew = fmaxf(mold, tmax);
          float al = __expf(mold - mnew);
          float p0 = mv[0] * __expf(vm0 - mnew);
          float p1 = mv[1] * __expf(vm1 - mnew);
          float p2 = mv[2] * __expf(vm2 - mnew);
          float p3 = mv[3] * __expf(vm3 - mnew);
          float ps = (p0 + p1) + (p2 + p3);
          float px = fmaf(p0, xv[0], fmaf(p1, xv[1], fmaf(p2, xv[2], p3 * xv[3])));
          slv[mt][r] = slv[mt][r] * al + ps;
          sav[mt][r] = sav[mt][r] * al + px;
          sm[mt][r] = mnew;
        }
    }
    __syncthreads();
  }
  // epilogue: merge 16 lanes (same kg group), write attn
#pragma unroll
  for (int mt = 0; mt < 2; ++mt)
#pragma unroll
    for (int r = 0; r < 4; ++r) {
      float m = sm[mt][r], l = slv[mt][r], a = sav[mt][r];
#pragma unroll
      for (int off = 1; off <= 8; off <<= 1) {
        float m2 = __shfl_xor(m, off);
        float l2 = __shfl_xor(l, off);
        float a2 = __shfl_xor(a, off);
        float M = fmaxf(m, m2);
        float e1 = __expf(m - M), e2 = __expf(m2 - M);
        l = l * e1 + l2 * e2;
        a = a * e1 + a2 * e2;
        m = M;
      }
      if (l15 == 0) {
        int q = (wave * 2 + mt) * 16 + kg * 4 + r;
        float inv = 1.f / l;
        attn_out[(b * LQ + q) * 8 + h * 2 + 0] = a * inv;
        attn_out[(b * LQ + q) * 8 + h * 2 + 1] = 1.f;  // sum_p over valid == 1 exactly
      }
    }
}

// ---------------- GRU: 1 block/batch, whh rows in VGPRs, h broadcast via readlane ----------------
__global__ __launch_bounds__(384) void k_gru(
    const float* __restrict__ whh, const float* __restrict__ bhh,
    const float* __restrict__ fwc, const float* __restrict__ attn,
    float* __restrict__ gout) {
  __shared__ float h_lds[128];
  __shared__ float ghx[256];
  __shared__ float ghn[128];
  __shared__ float xnl[128];
  const int g = threadIdx.x;
  const int b = blockIdx.x;
  float w[128];
#pragma unroll
  for (int e4 = 0; e4 < 32; ++e4) {
    float4 t = *(const float4*)(whh + g * 128 + e4 * 4);
    w[e4 * 4 + 0] = t.x; w[e4 * 4 + 1] = t.y;
    w[e4 * 4 + 2] = t.z; w[e4 * 4 + 3] = t.w;
  }
  const float bh = bhh[g];
  float fw[8];
  {
    float4 f0 = *(const float4*)(fwc + g * 12);
    float4 f1 = *(const float4*)(fwc + g * 12 + 4);
    fw[0] = f0.x; fw[1] = f0.y; fw[2] = f0.z; fw[3] = f0.w;
    fw[4] = f1.x; fw[5] = f1.y; fw[6] = f1.z; fw[7] = f1.w;
  }
  const float cg = fwc[g * 12 + 8];
  if (g < 128) h_lds[g] = 0.f;
  __syncthreads();
  const float* arow = attn + b * LQ * 8;
  for (int t = 0; t < LQ; ++t) {
    float hlo = h_lds[g & 63];
    float hhi = h_lds[64 + (g & 63)];
    float4 a0 = *(const float4*)(arow + t * 8);
    float4 a1 = *(const float4*)(arow + t * 8 + 4);
    float g0 = 0.f, g1 = 0.f, g2 = 0.f, g3 = 0.f;
#pragma unroll
    for (int e = 0; e < 64; e += 4) {
      g0 = fmaf(rdlane(hlo, e + 0), w[e + 0], g0);
      g1 = fmaf(rdlane(hlo, e + 1), w[e + 1], g1);
      g2 = fmaf(rdlane(hlo, e + 2), w[e + 2], g2);
      g3 = fmaf(rdlane(hlo, e + 3), w[e + 3], g3);
    }
#pragma unroll
    for (int e = 0; e < 64; e += 4) {
      g0 = fmaf(rdlane(hhi, e + 0), w[64 + e + 0], g0);
      g1 = fmaf(rdlane(hhi, e + 1), w[64 + e + 1], g1);
      g2 = fmaf(rdlane(hhi, e + 2), w[64 + e + 2], g2);
      g3 = fmaf(rdlane(hhi, e + 3), w[64 + e + 3], g3);
    }
    float gh = bh + ((g0 + g1) + (g2 + g3));
    float xg = cg + fw[0] * a0.x + fw[1] * a0.y + fw[2] * a0.z + fw[3] * a0.w
                  + fw[4] * a1.x + fw[5] * a1.y + fw[6] * a1.z + fw[7] * a1.w;
    if (g < 256) ghx[g] = gh + xg;
    else { ghn[g - 256] = gh; xnl[g - 256] = xg; }
    __syncthreads();
    if (g < 128) {
      float r = sigm(ghx[g]);
      float z = sigm(ghx[128 + g]);
      float n = tanh_f(fmaf(r, ghn[g], xnl[g]));
      float hn = fmaf(z, h_lds[g] - n, n);  // (1-z)n + z*h
      h_lds[g] = hn;
      gout[(b * LQ + t) * NH + g] = hn;
    }
    __syncthreads();
  }
}

// ---------------- pooling + MLP heads + signal equation ----------------
__global__ __launch_bounds__(256) void k_heads(
    const float* __restrict__ gout,
    const float* __restrict__ swT, const float* __restrict__ swM,
    const float* __restrict__ tw1, const float* __restrict__ tb1,
    const float* __restrict__ tw2, const float* __restrict__ tb2,
    const float* __restrict__ tw3, const float* __restrict__ tb3,
    const float* __restrict__ mw1, const float* __restrict__ mb1,
    const float* __restrict__ mw2, const float* __restrict__ mb2,
    const float* __restrict__ mw3, const float* __restrict__ mb3,
    const float* __restrict__ fav, const float* __restrict__ TRv,
    float* __restrict__ out) {
  __shared__ float hbuf[128 * 129];
  __shared__ float lT[128], lM[128], pT[128], pM[128];
  __shared__ float hidT[128], hidM[128];
  __shared__ float l1b[200], l2b[200];
  __shared__ float parts[4];
  __shared__ float scal[2];
  const int tid = threadIdx.x;
  const int b = blockIdx.x;
  for (int rep = 0; rep < 64; ++rep) {
    int i = rep * 256 + tid;
    hbuf[(i >> 7) * 129 + (i & 127)] = gout[b * (LQ * NH) + i];
  }
  __syncthreads();
  if (tid < 128) {
    float aT = 0.f, aM = 0.f;
    for (int j = 0; j < 128; ++j) {
      float v = hbuf[tid * 129 + j];
      aT = fmaf(v, swT[j], aT);
      aM = fmaf(v, swM[j], aM);
    }
    lT[tid] = aT; lM[tid] = aM;
  }
  __syncthreads();
  if (tid < 64) {
    float v0 = lT[tid], v1 = lT[tid + 64];
    float m = fmaxf(v0, v1);
    for (int off = 32; off > 0; off >>= 1) m = fmaxf(m, __shfl_xor(m, off));
    float p0 = __expf(v0 - m), p1 = __expf(v1 - m);
    float s = p0 + p1;
    for (int off = 32; off > 0; off >>= 1) s += __shfl_xor(s, off);
    float inv = 1.f / s;
    pT[tid] = p0 * inv; pT[tid + 64] = p1 * inv;
  } else if (tid < 128) {
    int l = tid - 64;
    float v0 = lM[l], v1 = lM[l + 64];
    float m = fmaxf(v0, v1);
    for (int off = 32; off > 0; off >>= 1) m = fmaxf(m, __shfl_xor(m, off));
    float p0 = __expf(v0 - m), p1 = __expf(v1 - m);
    float s = p0 + p1;
    for (int off = 32; off > 0; off >>= 1) s += __shfl_xor(s, off);
    float inv = 1.f / s;
    pM[l] = p0 * inv; pM[l + 64] = p1 * inv;
  }
  __syncthreads();
  if (tid < 128) {
    float aT = 0.f, aM = 0.f;
    for (int t = 0; t < 128; ++t) {
      float v = hbuf[t * 129 + tid];
      aT = fmaf(v, pT[t], aT);
      aM = fmaf(v, pM[t], aM);
    }
    hidT[tid] = aT; hidM[tid] = aM;
  }
  __syncthreads();
#pragma unroll 1
  for (int hd = 0; hd < 2; ++hd) {
    const float* in = hd ? hidM : hidT;
    const float* w1 = hd ? mw1 : tw1; const float* b1 = hd ? mb1 : tb1;
    const float* w2 = hd ? mw2 : tw2; const float* b2 = hd ? mb2 : tb2;
    const float* w3 = hd ? mw3 : tw3; const float* b3 = hd ? mb3 : tb3;
    if (tid < 200) {
      float acc = b1[tid];
      for (int j4 = 0; j4 < 32; ++j4) {
        float4 wv = *(const float4*)(w1 + tid * 128 + j4 * 4);
        acc += wv.x * in[j4 * 4] + wv.y * in[j4 * 4 + 1] + wv.z * in[j4 * 4 + 2] + wv.w * in[j4 * 4 + 3];
      }
      l1b[tid] = gelu_f(acc);
    }
    __syncthreads();
    if (tid < 200) {
      float acc = b2[tid];
      for (int k4 = 0; k4 < 50; ++k4) {
        float4 wv = *(const float4*)(w2 + tid * 200 + k4 * 4);
        acc += wv.x * l1b[k4 * 4] + wv.y * l1b[k4 * 4 + 1] + wv.z * l1b[k4 * 4 + 2] + wv.w * l1b[k4 * 4 + 3];
      }
      l2b[tid] = gelu_f(acc);
    }
    __syncthreads();
    float part = (tid < 200) ? l2b[tid] * w3[tid] : 0.f;
    for (int off = 32; off > 0; off >>= 1) part += __shfl_xor(part, off);
    if ((tid & 63) == 0) parts[tid >> 6] = part;
    __syncthreads();
    if (tid == 0) {
      float y = parts[0] + parts[1] + parts[2] + parts[3] + b3[0];
      float hi = hd ? 10.f : 5.f;
      float val = 0.1f + sigm(y) * (hi - 0.1f);
      scal[hd] = val;
      out[BS * SEQ + hd * BS + b] = val;
    }
    __syncthreads();
  }
  float T10 = scal[0], M0 = scal[1];
  float R1 = 1.f / T10;
  for (int i = tid; i < SEQ; i += 256) {
    float fa = fav[b * SEQ + i];
    float tr = TRv[b * SEQ + i];
    float E = __expf(-tr * R1);
    float s, c;
    __sincosf(fa, &s, &c);
    out[b * SEQ + i] = (1.f - E) * s / (1.f - c * E) * M0;
  }
}

// ---------------- launch ----------------
extern "C" void kernel_launch(void* const* d_in, const int* in_sizes, int n_in,
                              void* d_out, int out_size, void* d_ws, size_t ws_size,
                              hipStream_t stream) {
  const float* Xfa = (const float*)d_in[0];
  const float* fav = (const float*)d_in[1];
  const void*  mraw = d_in[2];
  const float* TRv = (const float*)d_in[4];
  const float* lw = (const float*)d_in[5];
  const float* lb = (const float*)d_in[6];
  const float* pw = (const float*)d_in[7];
  const float* pb = (const float*)d_in[8];
  const float* qw = (const float*)d_in[9];
  const float* qb = (const float*)d_in[10];
  const float* kw = (const float*)d_in[11];
  const float* kb = (const float*)d_in[12];
  const float* aow = (const float*)d_in[13];
  const float* aob = (const float*)d_in[14];
  const float* wih = (const float*)d_in[15];
  const float* whh = (const float*)d_in[16];
  const float* bih = (const float*)d_in[17];
  const float* bhh = (const float*)d_in[18];
  const float* swT = (const float*)d_in[19];
  const float* swM = (const float*)d_in[20];
  const float* tw1 = (const float*)d_in[21];
  const float* tb1 = (const float*)d_in[22];
  const float* tw2 = (const float*)d_in[23];
  const float* tb2 = (const float*)d_in[24];
  const float* tw3 = (const float*)d_in[25];
  const float* tb3 = (const float*)d_in[26];
  const float* mw1 = (const float*)d_in[27];
  const float* mb1 = (const float*)d_in[28];
  const float* mw2 = (const float*)d_in[29];
  const float* mb2 = (const float*)d_in[30];
  const float* mw3 = (const float*)d_in[31];
  const float* mb3 = (const float*)d_in[32];
  float* out = (float*)d_out;
  char* ws = (char*)d_ws;

  unsigned short* qbf = (unsigned short*)ws;            // 32768 B
  float* attn_ws = (float*)(ws + 32768);                // 262144 B
  float* fwc = (float*)(ws + 32768 + 262144);           // 18432 B
  float* maskf = (float*)(ws + 313344);                 // 524288 B
  int* flag = (int*)(ws + 837632);                      // 4 B (pad to 128)
  float* gout = (float*)(ws + 837760);                  // 4194304 B

  k_detect<<<1, 64, 0, stream>>>((const unsigned*)mraw, flag);
  k_norm<<<512, 256, 0, stream>>>(mraw, flag, maskf);
  k_qproj<<<8, 256, 0, stream>>>(qw, qb, lw, lb, pw, pb, qbf);
  k_fold<<<1, 384, 0, stream>>>(wih, bih, aow, aob, fwc);
  k_attn<<<256, 256, 0, stream>>>(Xfa, maskf, fav, kw, kb, lw, lb, pw, pb, qbf, attn_ws);
  k_gru<<<64, 384, 0, stream>>>(whh, bhh, fwc, attn_ws, gout);
  k_heads<<<64, 256, 0, stream>>>(gout, swT, swM, tw1, tb1, tw2, tb2, tw3, tb3,
                                  mw1, mb1, mw2, mb2, mw3, mb3, fav, TRv, out);
}